// Round 18
// baseline (350.402 us; speedup 1.0000x reference)
//
#include <hip/hip_runtime.h>

#define NN 50000
#define EE 800000
#define FIN 256
#define FH 128
#define FC 64
#define LPA_ITERS 10
#define NBLK 196   // (NN + 255) / 256
#define G1X 782    // (NN + 63) / 64   GEMM row-blocks
#define SPB 3125   // (NN + 15) / 16   quarter-wave spmm blocks
#define SP128B 6250  // (NN + 7) / 8   half-wave spmm blocks
#define EBLK 3125  // (EE + 255) / 256 edge blocks

// GEMM1 virtual-block slices paired with CSR-chain kernels (sized ~partner dur)
#define G1_S1 782   // p1 || accum
#define G1_S2 882   // p2 || finish
#define G1_S3 1382  // p3 || scatter
#define G1_TOT 1564 // p4 || rowscale gets the rest

typedef __attribute__((ext_vector_type(8))) short short8v;  // 8 bf16 (4 VGPRs)
typedef __attribute__((ext_vector_type(4))) float f32x4;    // MFMA accum

__device__ __forceinline__ int edge_at(const int* __restrict__ ei, int is32, int which, int e) {
    int idx = which * EE + e;
    return is32 ? ei[idx] : ei[2 * idx];
}

__device__ __forceinline__ unsigned short bf16_rne(float f) {
    unsigned u = __float_as_uint(f);
    return (unsigned short)((u + 0x7FFFu + ((u >> 16) & 1u)) >> 16);
}
__device__ __forceinline__ unsigned packbf2(float a, float b) {
    return (unsigned)bf16_rne(a) | ((unsigned)bf16_rne(b) << 16);
}

__device__ __forceinline__ void accum_body(int pb, const int* __restrict__ ei,
                                           const int* __restrict__ flag,
                                           int* __restrict__ cnt,
                                           int* __restrict__ slot) {
    int e = pb * 256 + (int)threadIdx.x;
    if (e >= EE) return;
    int is32 = *flag;
    int r = edge_at(ei, is32, 0, e);
    slot[e] = atomicAdd(&cnt[r], 1);
}

__global__ __launch_bounds__(256) void scan1_k(const int* __restrict__ cnt,
                                               int* __restrict__ start,
                                               int* __restrict__ bsum,
                                               int* __restrict__ blockhist) {
    __shared__ int wtot[4];
    __shared__ int hist[64];
    int t = threadIdx.x, blk = blockIdx.x;
    int i = blk * 256 + t;
    if (t < 64) hist[t] = 0;
    __syncthreads();
    int c = (i < NN) ? cnt[i] : 0;
    if (i < NN) atomicAdd(&hist[c < 63 ? c : 63], 1);
    int lane = t & 63, w = t >> 6;
    int s = c;
    for (int d = 1; d < 64; d <<= 1) {
        int u = __shfl_up(s, d, 64);
        if (lane >= d) s += u;
    }
    if (lane == 63) wtot[w] = s;
    __syncthreads();
    int woff = 0;
    for (int j = 0; j < 4; ++j)
        if (j < w) woff += wtot[j];
    int excl = s - c + woff;
    if (i < NN) start[i] = excl;
    if (t == 255) bsum[blk] = excl + c;
    if (t < 64) blockhist[t * NBLK + blk] = hist[t];
}

__global__ void scan2_k(int* __restrict__ bsum, int* __restrict__ blockhist) {
    __shared__ int wtot[4];
    __shared__ int btot[64];
    int t = threadIdx.x;
    int lane = t & 63, w = t >> 6;
    int v = (t < NBLK) ? bsum[t] : 0;
    int s = v;
    for (int d = 1; d < 64; d <<= 1) {
        int u = __shfl_up(s, d, 64);
        if (lane >= d) s += u;
    }
    if (lane == 63) wtot[w] = s;
    __syncthreads();
    int woff = 0;
    for (int j = 0; j < 4; ++j)
        if (j < w) woff += wtot[j];
    if (t < NBLK) bsum[t] = s - v + woff;
    if (t < 64) {
        int run = 0;
        for (int j = 0; j < NBLK; ++j) {
            int idx = t * NBLK + j;
            int tmp = blockhist[idx];
            blockhist[idx] = run;
            run += tmp;
        }
        btot[t] = run;
    }
    __syncthreads();
    if (t < 64) {
        int bv = btot[t];
        int bs = bv;
        for (int d = 1; d < 64; d <<= 1) {
            int u = __shfl_up(bs, d, 64);
            if (lane >= d) bs += u;
        }
        int base = bs - bv;
        for (int j = 0; j < NBLK; ++j) blockhist[t * NBLK + j] += base;
    }
}

__device__ __forceinline__ void finish_body(int blk, const int* __restrict__ cnt,
                                            int* __restrict__ start,
                                            const int* __restrict__ bsum,
                                            const int* __restrict__ blockhist,
                                            int* __restrict__ perm) {
    __shared__ int hist[64];
    int t = threadIdx.x;
    int i = blk * 256 + t;
    if (t < 64) hist[t] = 0;
    __syncthreads();
    if (i < NN) {
        start[i] += bsum[blk];
        int c = cnt[i];
        int b = c < 63 ? c : 63;
        int rank = atomicAdd(&hist[b], 1);
        perm[blockhist[b * NBLK + blk] + rank] = i;
    }
}

__device__ __forceinline__ void scatter_body(int pb, const int* __restrict__ ei,
                                             const int* __restrict__ flag,
                                             const float* __restrict__ ea,
                                             const int* __restrict__ start,
                                             const int* __restrict__ slot,
                                             uint2* __restrict__ csr) {
    int e = pb * 256 + (int)threadIdx.x;
    if (e >= EE) return;
    int is32 = *flag;
    int r = edge_at(ei, is32, 0, e);
    int c = edge_at(ei, is32, 1, e);
    csr[start[r] + slot[e]] = make_uint2((unsigned)c, __float_as_uint(ea[e]));
}

__device__ __forceinline__ void rowscale_body(int pb, const int* __restrict__ start,
                                              const int* __restrict__ cnt,
                                              const uint2* __restrict__ csr,
                                              float* __restrict__ deginv) {
    int t = threadIdx.x;
    int r = pb * 16 + (t >> 4);
    if (r >= NN) return;
    int fl = t & 15;
    int s = start[r], n = cnt[r];
    float sum = 0.f;
    for (int k = fl; k < n; k += 16) sum += __uint_as_float(csr[s + k].y);
    for (int d = 1; d < 16; d <<= 1) sum += __shfl_xor(sum, d, 16);
    if (fl == 0) deginv[r] = sum > 0.f ? 1.f / sum : 0.f;
}

// Fused prep: cast (3125) | wcvt1 (128) | wcvt2 (32) | detect (1).
__global__ __launch_bounds__(256) void prep_k(const float* __restrict__ W1,
                                              const float* __restrict__ W2,
                                              const float* __restrict__ soft,
                                              const unsigned int* __restrict__ eiw,
                                              int* __restrict__ flag,
                                              short* __restrict__ w1h, short* __restrict__ w1l,
                                              short* __restrict__ w2h, short* __restrict__ w2l,
                                              uint2* __restrict__ sbf) {
    int b = blockIdx.x, t = threadIdx.x;
    if (b < 3125) {  // soft -> bf16
        int i = b * 256 + t;
        float4 f = ((const float4*)soft)[i];
        sbf[i] = make_uint2(packbf2(f.x, f.y), packbf2(f.z, f.w));
    } else if (b < 3125 + 128) {  // W1 split-transpose
        int i = (b - 3125) * 256 + t;
        int k = i / FH, n = i - k * FH;
        float f = W1[i];
        unsigned short h = bf16_rne(f);
        float hf = __uint_as_float((unsigned)h << 16);
        w1h[n * FIN + k] = (short)h;
        w1l[n * FIN + k] = (short)bf16_rne(f - hf);
    } else if (b < 3125 + 128 + 32) {  // W2 split-transpose
        int i = (b - 3125 - 128) * 256 + t;
        int k = i / FC, n = i - k * FC;
        float f = W2[i];
        unsigned short h = bf16_rne(f);
        float hf = __uint_as_float((unsigned)h << 16);
        w2h[n * FH + k] = (short)h;
        w2l[n * FH + k] = (short)bf16_rne(f - hf);
    } else {  // int64-vs-int32 layout detect
        int any = 0;
        for (int i = 1 + 2 * t; i < 2048; i += 512)
            if (eiw[i] != 0u) any = 1;
        if (any) atomicOr(flag, 1);
    }
}

// ---------- GEMM body (R9-exact config) ----------
template <int KDIM, int NCOLT, int NF, int ABF, int CBF>
__device__ __forceinline__ void mgemm2_body(int bx, int cb,
                                            const void* __restrict__ Ap,
                                            const short* __restrict__ Bhi0,
                                            const short* __restrict__ Blo0,
                                            void* __restrict__ Cp, int M) {
    static_assert((size_t)NF * 16 * 72 * 2 * 2 < 49152, "LDS must stay well under 64KB");
    __shared__ short bh[NF * 16][72];
    __shared__ short bl[NF * 16][72];
    const int NSTG = KDIM / 64;
    const int NCH = NF / 2;
    int t = threadIdx.x;
    const short* Bhi = Bhi0 + (size_t)cb * (NF * 16) * KDIM;
    const short* Blo = Blo0 + (size_t)cb * (NF * 16) * KDIM;
    int wid = t >> 6, l = t & 63, l15 = l & 15, lq = l >> 4;
    int row = bx * 64 + wid * 16 + l15;
    bool rv = row < M;
    f32x4 acc[NF];
#pragma unroll
    for (int j = 0; j < NF; ++j) acc[j] = (f32x4){0.f, 0.f, 0.f, 0.f};

    short8v rh[NCH], rl[NCH];
    float4 af[2][4];
    short8v ab_[2][2];
#pragma unroll
    for (int b = 0; b < 2; ++b) {
        if (ABF) {
            ab_[b][0] = (short8v){0, 0, 0, 0, 0, 0, 0, 0};
            ab_[b][1] = (short8v){0, 0, 0, 0, 0, 0, 0, 0};
        } else {
#pragma unroll
            for (int q = 0; q < 4; ++q) af[b][q] = make_float4(0.f, 0.f, 0.f, 0.f);
        }
    }

    auto loadB = [&](int k0) {
#pragma unroll
        for (int j = 0; j < NCH; ++j) {
            int c = t + j * 256;
            int col = c >> 3;
            int kk = (c & 7) * 8;
            rh[j] = *(const short8v*)&Bhi[(size_t)col * KDIM + k0 + kk];
            rl[j] = *(const short8v*)&Blo[(size_t)col * KDIM + k0 + kk];
        }
    };
    auto loadA = [&](int k0, int buf) {
        if (!rv) return;
        if (ABF) {
            const short* A = (const short*)Ap;
            ab_[buf][0] = *(const short8v*)&A[(size_t)row * KDIM + k0 + 8 * lq];
            ab_[buf][1] = *(const short8v*)&A[(size_t)row * KDIM + k0 + 32 + 8 * lq];
        } else {
            const float* A = (const float*)Ap;
            const float4* p0 = (const float4*)&A[(size_t)row * KDIM + k0 + 8 * lq];
            af[buf][0] = p0[0];
            af[buf][1] = p0[1];
            const float4* p1 = (const float4*)&A[(size_t)row * KDIM + k0 + 32 + 8 * lq];
            af[buf][2] = p1[0];
            af[buf][3] = p1[1];
        }
    };

    loadB(0);
    loadA(0, 0);
#pragma unroll
    for (int sg = 0; sg < NSTG; ++sg) {
        __syncthreads();
#pragma unroll
        for (int j = 0; j < NCH; ++j) {
            int c = t + j * 256;
            int col = c >> 3;
            int kk = (c & 7) * 8;
            *(short8v*)&bh[col][kk] = rh[j];
            *(short8v*)&bl[col][kk] = rl[j];
        }
        __syncthreads();
        if (sg + 1 < NSTG) {
            loadB((sg + 1) * 64);
            loadA((sg + 1) * 64, (sg + 1) & 1);
        }
        int cbuf = sg & 1;
#pragma unroll
        for (int ks = 0; ks < 2; ++ks) {
            short8v ahi, alo;
            if (ABF) {
                ahi = ab_[cbuf][ks];
            } else {
                float av[8];
                float4 xa = af[cbuf][ks * 2], xb = af[cbuf][ks * 2 + 1];
                av[0] = xa.x; av[1] = xa.y; av[2] = xa.z; av[3] = xa.w;
                av[4] = xb.x; av[5] = xb.y; av[6] = xb.z; av[7] = xb.w;
#pragma unroll
                for (int e = 0; e < 8; ++e) {
                    unsigned short h = bf16_rne(av[e]);
                    float hf = __uint_as_float((unsigned)h << 16);
                    ahi[e] = (short)h;
                    alo[e] = (short)bf16_rne(av[e] - hf);
                }
            }
#pragma unroll
            for (int j = 0; j < NF; ++j) {
                int col = j * 16 + l15;
                short8v fh = *(const short8v*)&bh[col][ks * 32 + 8 * lq];
                short8v fo = *(const short8v*)&bl[col][ks * 32 + 8 * lq];
                acc[j] = __builtin_amdgcn_mfma_f32_16x16x32_bf16(ahi, fh, acc[j], 0, 0, 0);
                acc[j] = __builtin_amdgcn_mfma_f32_16x16x32_bf16(ahi, fo, acc[j], 0, 0, 0);
                if (!ABF)
                    acc[j] = __builtin_amdgcn_mfma_f32_16x16x32_bf16(alo, fh, acc[j], 0, 0, 0);
            }
        }
    }
    int rbase = bx * 64 + wid * 16 + 4 * lq;
#pragma unroll
    for (int j = 0; j < NF; ++j) {
        int col = cb * (NF * 16) + j * 16 + l15;
#pragma unroll
        for (int e = 0; e < 4; ++e) {
            int r = rbase + e;
            if (r < M) {
                if (CBF)
                    ((unsigned short*)Cp)[(size_t)r * NCOLT + col] = bf16_rne(acc[j][e]);
                else
                    ((float*)Cp)[(size_t)r * NCOLT + col] = acc[j][e];
            }
        }
    }
}

__device__ __forceinline__ void gemm1_v(int v, const float* __restrict__ x,
                                        const short* __restrict__ w1h,
                                        const short* __restrict__ w1l,
                                        unsigned short* __restrict__ t1) {
    mgemm2_body<FIN, FH, 4, 0, 1>(v % G1X, v / G1X, x, w1h, w1l, t1, NN);
}

// ---------- spmm bodies ----------
__device__ __forceinline__ void spmm128b_body(int pb, const int* __restrict__ perm,
                                              const int* __restrict__ start,
                                              const int* __restrict__ cnt,
                                              const float* __restrict__ deginv,
                                              const uint2* __restrict__ csr,
                                              const uint2* __restrict__ mb,
                                              uint2* __restrict__ outb,
                                              const float* __restrict__ bias) {
    int t = threadIdx.x;
    int p = pb * 8 + (t >> 5);
    if (p >= NN) return;
    int r = perm[p];
    int fl = t & 31;
    float4 acc = make_float4(0.f, 0.f, 0.f, 0.f);
    int s = start[r], n = cnt[r];
    int k = 0;
    for (; k + 8 <= n; k += 8) {
        uint2 ev[8];
        uint2 gv[8];
#pragma unroll
        for (int u = 0; u < 8; ++u) ev[u] = csr[s + k + u];
#pragma unroll
        for (int u = 0; u < 8; ++u) gv[u] = mb[(size_t)ev[u].x * 32 + fl];
#pragma unroll
        for (int u = 0; u < 8; ++u) {
            float v = __uint_as_float(ev[u].y);
            acc.x = fmaf(v, __uint_as_float(gv[u].x << 16), acc.x);
            acc.y = fmaf(v, __uint_as_float(gv[u].x & 0xFFFF0000u), acc.y);
            acc.z = fmaf(v, __uint_as_float(gv[u].y << 16), acc.z);
            acc.w = fmaf(v, __uint_as_float(gv[u].y & 0xFFFF0000u), acc.w);
        }
    }
    for (; k < n; ++k) {
        uint2 e = csr[s + k];
        float v = __uint_as_float(e.y);
        uint2 g = mb[(size_t)e.x * 32 + fl];
        acc.x = fmaf(v, __uint_as_float(g.x << 16), acc.x);
        acc.y = fmaf(v, __uint_as_float(g.x & 0xFFFF0000u), acc.y);
        acc.z = fmaf(v, __uint_as_float(g.y << 16), acc.z);
        acc.w = fmaf(v, __uint_as_float(g.y & 0xFFFF0000u), acc.w);
    }
    float dv = deginv[r];
    float4 b = ((const float4*)bias)[fl];
    acc.x = fmaxf(fmaf(acc.x, dv, b.x), 0.f);
    acc.y = fmaxf(fmaf(acc.y, dv, b.y), 0.f);
    acc.z = fmaxf(fmaf(acc.z, dv, b.z), 0.f);
    acc.w = fmaxf(fmaf(acc.w, dv, b.w), 0.f);
    outb[(size_t)r * 32 + fl] = make_uint2(packbf2(acc.x, acc.y), packbf2(acc.z, acc.w));
}

// SpMM F=64 bf16-in: quarter-wave; optional bias; bf16 or f32 out.
__device__ __forceinline__ void spmm64b_body(int pb, const int* __restrict__ perm,
                                             const int* __restrict__ start,
                                             const int* __restrict__ cnt,
                                             const float* __restrict__ deginv,
                                             const uint2* __restrict__ csr,
                                             const uint2* __restrict__ mb,
                                             void* __restrict__ outp,
                                             const float* __restrict__ bias,
                                             int f32out) {
    int t = threadIdx.x;
    int p = pb * 16 + (t >> 4);
    if (p >= NN) return;
    int r = perm[p];
    int fl = t & 15;
    float4 acc = make_float4(0.f, 0.f, 0.f, 0.f);
    int s = start[r], n = cnt[r];
    int k = 0;
    for (; k + 8 <= n; k += 8) {
        uint2 ev[8];
        uint2 gv[8];
#pragma unroll
        for (int u = 0; u < 8; ++u) ev[u] = csr[s + k + u];
#pragma unroll
        for (int u = 0; u < 8; ++u) gv[u] = mb[(size_t)ev[u].x * 16 + fl];
#pragma unroll
        for (int u = 0; u < 8; ++u) {
            float v = __uint_as_float(ev[u].y);
            acc.x = fmaf(v, __uint_as_float(gv[u].x << 16), acc.x);
            acc.y = fmaf(v, __uint_as_float(gv[u].x & 0xFFFF0000u), acc.y);
            acc.z = fmaf(v, __uint_as_float(gv[u].y << 16), acc.z);
            acc.w = fmaf(v, __uint_as_float(gv[u].y & 0xFFFF0000u), acc.w);
        }
    }
    for (; k < n; ++k) {
        uint2 e = csr[s + k];
        float v = __uint_as_float(e.y);
        uint2 g = mb[(size_t)e.x * 16 + fl];
        acc.x = fmaf(v, __uint_as_float(g.x << 16), acc.x);
        acc.y = fmaf(v, __uint_as_float(g.x & 0xFFFF0000u), acc.y);
        acc.z = fmaf(v, __uint_as_float(g.y << 16), acc.z);
        acc.w = fmaf(v, __uint_as_float(g.y & 0xFFFF0000u), acc.w);
    }
    float dv = deginv[r];
    acc.x *= dv; acc.y *= dv; acc.z *= dv; acc.w *= dv;
    if (bias) {
        float4 b = ((const float4*)bias)[fl];
        acc.x += b.x; acc.y += b.y; acc.z += b.z; acc.w += b.w;
    }
    if (f32out) {
        ((float4*)outp)[(size_t)r * 16 + fl] = acc;
    } else {
        ((uint2*)outp)[(size_t)r * 16 + fl] =
            make_uint2(packbf2(acc.x, acc.y), packbf2(acc.z, acc.w));
    }
}

// ---------- fused kernels ----------

// P1: accum (3125, LONG POLE — dispatched first so the atomic chain starts
// at t=0) || GEMM1 slice [0,782).
__global__ __launch_bounds__(256) void p1_k(const float* __restrict__ x,
                                            const short* __restrict__ w1h,
                                            const short* __restrict__ w1l,
                                            unsigned short* __restrict__ t1,
                                            const int* __restrict__ ei,
                                            const int* __restrict__ flag,
                                            int* __restrict__ cnt,
                                            int* __restrict__ slot) {
    int b = blockIdx.x;
    if (b < EBLK) accum_body(b, ei, flag, cnt, slot);
    else gemm1_v(b - EBLK, x, w1h, w1l, t1);
}

// P2: GEMM1 slice [782,882) || finish (196)
__global__ __launch_bounds__(256) void p2_k(const float* __restrict__ x,
                                            const short* __restrict__ w1h,
                                            const short* __restrict__ w1l,
                                            unsigned short* __restrict__ t1,
                                            const int* __restrict__ cnt,
                                            int* __restrict__ start,
                                            const int* __restrict__ bsum,
                                            const int* __restrict__ bhist,
                                            int* __restrict__ perm) {
    int b = blockIdx.x;
    if (b < G1_S2 - G1_S1) gemm1_v(G1_S1 + b, x, w1h, w1l, t1);
    else finish_body(b - (G1_S2 - G1_S1), cnt, start, bsum, bhist, perm);
}

// P3: scatter (3125, long pole first) || GEMM1 slice [882,1382)
__global__ __launch_bounds__(256) void p3_k(const float* __restrict__ x,
                                            const short* __restrict__ w1h,
                                            const short* __restrict__ w1l,
                                            unsigned short* __restrict__ t1,
                                            const int* __restrict__ ei,
                                            const int* __restrict__ flag,
                                            const float* __restrict__ ea,
                                            const int* __restrict__ start,
                                            const int* __restrict__ slot,
                                            uint2* __restrict__ csr) {
    int b = blockIdx.x;
    if (b < EBLK) scatter_body(b, ei, flag, ea, start, slot, csr);
    else gemm1_v(G1_S2 + (b - EBLK), x, w1h, w1l, t1);
}

// P4: GEMM1 slice [1382,1564) (long pole first) || rowscale (3125)
__global__ __launch_bounds__(256) void p4_k(const float* __restrict__ x,
                                            const short* __restrict__ w1h,
                                            const short* __restrict__ w1l,
                                            unsigned short* __restrict__ t1,
                                            const int* __restrict__ start,
                                            const int* __restrict__ cnt,
                                            const uint2* __restrict__ csr,
                                            float* __restrict__ dinv) {
    int b = blockIdx.x;
    if (b < G1_TOT - G1_S3) gemm1_v(G1_S3 + b, x, w1h, w1l, t1);
    else rowscale_body(b - (G1_TOT - G1_S3), start, cnt, csr, dinv);
}

// F2: spmm128b (6250) || LPA it0 (sbf -> lA)
__global__ __launch_bounds__(256) void f2_k(const int* __restrict__ perm,
                                            const int* __restrict__ start,
                                            const int* __restrict__ cnt,
                                            const float* __restrict__ dinv,
                                            const uint2* __restrict__ csr,
                                            const uint2* __restrict__ t1,
                                            uint2* __restrict__ h,
                                            const float* __restrict__ b1,
                                            const uint2* __restrict__ sbf,
                                            uint2* __restrict__ lA) {
    int b = blockIdx.x;
    if (b < SP128B)
        spmm128b_body(b, perm, start, cnt, dinv, csr, t1, h, b1);
    else
        spmm64b_body(b - SP128B, perm, start, cnt, dinv, csr, sbf, lA, nullptr, 0);
}

// F3: GEMM2 -> t2 bf16 (782) || LPA it1 (lA -> lB)
__global__ __launch_bounds__(256) void f3_k(const unsigned short* __restrict__ h,
                                            const short* __restrict__ w2h,
                                            const short* __restrict__ w2l,
                                            unsigned short* __restrict__ t2,
                                            const int* __restrict__ perm,
                                            const int* __restrict__ start,
                                            const int* __restrict__ cnt,
                                            const float* __restrict__ dinv,
                                            const uint2* __restrict__ csr,
                                            const uint2* __restrict__ lA,
                                            uint2* __restrict__ lB) {
    int b = blockIdx.x;
    if (b < G1X)
        mgemm2_body<FH, FC, 4, 1, 1>(b, 0, h, w2h, w2l, t2, NN);
    else
        spmm64b_body(b - G1X, perm, start, cnt, dinv, csr, lA, lB, nullptr, 0);
}

// F4: conv2 spmm from bf16 t2 (+b2, f32 out) (3125) || LPA it2 (lB -> lA)
__global__ __launch_bounds__(256) void f4_k(const int* __restrict__ perm,
                                            const int* __restrict__ start,
                                            const int* __restrict__ cnt,
                                            const float* __restrict__ dinv,
                                            const uint2* __restrict__ csr,
                                            const uint2* __restrict__ t2b,
                                            float* __restrict__ out,
                                            const float* __restrict__ b2,
                                            const uint2* __restrict__ lB,
                                            uint2* __restrict__ lA) {
    int b = blockIdx.x;
    if (b < SPB)
        spmm64b_body(b, perm, start, cnt, dinv, csr, t2b, out, b2, 1);
    else
        spmm64b_body(b - SPB, perm, start, cnt, dinv, csr, lB, lA, nullptr, 0);
}

// Standalone LPA kernel for iters 3..9.
__global__ __launch_bounds__(256) void spmm64b_k(const int* __restrict__ perm,
                                                 const int* __restrict__ start,
                                                 const int* __restrict__ cnt,
                                                 const float* __restrict__ deginv,
                                                 const uint2* __restrict__ csr,
                                                 const uint2* __restrict__ mb,
                                                 void* __restrict__ outp,
                                                 int f32out) {
    spmm64b_body(blockIdx.x, perm, start, cnt, deginv, csr, mb, outp, nullptr, f32out);
}

extern "C" void kernel_launch(void* const* d_in, const int* in_sizes, int n_in,
                              void* d_out, int out_size, void* d_ws, size_t ws_size,
                              hipStream_t stream) {
    const float* x    = (const float*)d_in[0];
    const float* soft = (const float*)d_in[1];
    const int*   ei   = (const int*)d_in[2];
    const float* ea   = (const float*)d_in[3];
    const float* W1   = (const float*)d_in[4];
    const float* b1   = (const float*)d_in[5];
    const float* W2   = (const float*)d_in[6];
    const float* b2   = (const float*)d_in[7];
    float* out  = (float*)d_out;                 // [N, C]
    float* labB = out + (size_t)NN * FC;         // [N, C] second output

    char* ws = (char*)d_ws;
    size_t off = 0;
    auto alloc = [&](size_t b) { size_t o = off; off += (b + 255) & ~(size_t)255; return o; };
    size_t o_misc  = alloc(256);                      // [0] = layout flag
    size_t o_cnt   = alloc((size_t)NN * 4);
    size_t zero_end = off;
    size_t o_start = alloc((size_t)NN * 4);
    size_t o_perm  = alloc((size_t)NN * 4);
    size_t o_dinv  = alloc((size_t)NN * 4);
    size_t o_bsum  = alloc((size_t)NBLK * 4);
    size_t o_bhist = alloc((size_t)64 * NBLK * 4);
    size_t o_slot  = alloc((size_t)EE * 4);
    size_t o_csr   = alloc((size_t)EE * 8);           // packed uint2 {col, raw ea}
    size_t o_w1h   = alloc((size_t)FIN * FH * 2);     // W1^T split-bf16
    size_t o_w1l   = alloc((size_t)FIN * FH * 2);
    size_t o_w2h   = alloc((size_t)FH * FC * 2);      // W2^T split-bf16
    size_t o_w2l   = alloc((size_t)FH * FC * 2);
    size_t o_t1    = alloc((size_t)NN * FH * 2);      // xW1, bf16
    size_t o_h     = alloc((size_t)NN * FH * 2);      // relu(spmm)+b1, bf16
    size_t o_t2    = alloc((size_t)NN * FC * 2);      // hW2, bf16
    size_t o_sbf   = alloc((size_t)NN * FC * 2);      // soft_labels bf16
    size_t o_lA    = alloc((size_t)NN * FC * 2);      // LPA ping
    size_t o_lB    = alloc((size_t)NN * FC * 2);      // LPA pong
    if (off > ws_size) return;  // insufficient scratch -> visible failure

    int*   misc  = (int*)(ws + o_misc);
    int*   cnt   = (int*)(ws + o_cnt);
    int*   start = (int*)(ws + o_start);
    int*   perm  = (int*)(ws + o_perm);
    float* dinv  = (float*)(ws + o_dinv);
    int*   bsum  = (int*)(ws + o_bsum);
    int*   bhist = (int*)(ws + o_bhist);
    int*   slot  = (int*)(ws + o_slot);
    uint2* csr   = (uint2*)(ws + o_csr);
    short* w1h   = (short*)(ws + o_w1h);
    short* w1l   = (short*)(ws + o_w1l);
    short* w2h   = (short*)(ws + o_w2h);
    short* w2l   = (short*)(ws + o_w2l);
    unsigned short* t1 = (unsigned short*)(ws + o_t1);
    uint2* h     = (uint2*)(ws + o_h);
    unsigned short* t2 = (unsigned short*)(ws + o_t2);
    uint2* sbf   = (uint2*)(ws + o_sbf);
    uint2* lA    = (uint2*)(ws + o_lA);
    uint2* lB    = (uint2*)(ws + o_lB);

    hipMemsetAsync(d_ws, 0, zero_end, stream);
    prep_k<<<3125 + 128 + 32 + 1, 256, 0, stream>>>(W1, W2, soft, (const unsigned int*)ei,
                                                    &misc[0], w1h, w1l, w2h, w2l, sbf);

    // CSR chain, each stage carrying a GEMM1 slice; long pole dispatched first.
    p1_k<<<EBLK + G1_S1, 256, 0, stream>>>(x, w1h, w1l, t1, ei, misc, cnt, slot);
    scan1_k<<<NBLK, 256, 0, stream>>>(cnt, start, bsum, bhist);
    scan2_k<<<1, 256, 0, stream>>>(bsum, bhist);
    p2_k<<<(G1_S2 - G1_S1) + NBLK, 256, 0, stream>>>(x, w1h, w1l, t1, cnt, start, bsum,
                                                     bhist, perm);
    p3_k<<<EBLK + (G1_S3 - G1_S2), 256, 0, stream>>>(x, w1h, w1l, t1, ei, misc, ea,
                                                     start, slot, csr);
    p4_k<<<(G1_TOT - G1_S3) + SPB, 256, 0, stream>>>(x, w1h, w1l, t1, start, cnt, csr,
                                                     dinv);

    // Fused GCN stage || independent LPA iteration.
    f2_k<<<SP128B + SPB, 256, 0, stream>>>(perm, start, cnt, dinv, csr,
                                           (const uint2*)t1, h, b1, sbf, lA);
    f3_k<<<G1X + SPB, 256, 0, stream>>>((const unsigned short*)h, w2h, w2l, t2,
                                        perm, start, cnt, dinv, csr, lA, lB);
    f4_k<<<SPB + SPB, 256, 0, stream>>>(perm, start, cnt, dinv, csr,
                                        (const uint2*)t2, out, b2, lB, lA);

    // LPA iters 3..9 standalone (it9 writes f32 to labB).
    const uint2* src = lA;
    uint2* dst = lB;
    for (int it = 3; it < LPA_ITERS; ++it) {
        int last = (it == LPA_ITERS - 1);
        spmm64b_k<<<SPB, 256, 0, stream>>>(perm, start, cnt, dinv, csr, src,
                                           last ? (void*)labB : (void*)dst, last);
        src = dst;
        dst = (dst == lA) ? lB : lA;
    }
}

// Round 19
// 337.945 us; speedup vs baseline: 1.0369x; 1.0369x over previous
//
#include <hip/hip_runtime.h>

#define NN 50000
#define EE 800000
#define FIN 256
#define FH 128
#define FC 64
#define LPA_ITERS 10
#define NBLK 196   // (NN + 255) / 256
#define G1X 782    // (NN + 63) / 64   GEMM row-blocks
#define SPB 3125   // (NN + 15) / 16   quarter-wave spmm blocks
#define SP128B 6250  // (NN + 7) / 8   half-wave spmm blocks
#define EBLK 3125  // (EE + 255) / 256 edge blocks

// GEMM1 virtual-block slices paired with CSR-chain kernels (sized ~partner dur)
#define G1_S1 782   // p1 || accum
#define G1_S2 882   // p2 || finish
#define G1_S3 1382  // p3 || scatter
#define G1_TOT 1564 // p4 || rowscale gets the rest

typedef __attribute__((ext_vector_type(8))) short short8v;  // 8 bf16 (4 VGPRs)
typedef __attribute__((ext_vector_type(4))) float f32x4;    // MFMA accum

__device__ __forceinline__ int edge_at(const int* __restrict__ ei, int is32, int which, int e) {
    int idx = which * EE + e;
    return is32 ? ei[idx] : ei[2 * idx];
}

__device__ __forceinline__ unsigned short bf16_rne(float f) {
    unsigned u = __float_as_uint(f);
    return (unsigned short)((u + 0x7FFFu + ((u >> 16) & 1u)) >> 16);
}
__device__ __forceinline__ unsigned packbf2(float a, float b) {
    return (unsigned)bf16_rne(a) | ((unsigned)bf16_rne(b) << 16);
}

__device__ __forceinline__ void accum_body(int pb, const int* __restrict__ ei,
                                           const int* __restrict__ flag,
                                           int* __restrict__ cnt,
                                           int* __restrict__ slot) {
    int e = pb * 256 + (int)threadIdx.x;
    if (e >= EE) return;
    int is32 = *flag;
    int r = edge_at(ei, is32, 0, e);
    slot[e] = atomicAdd(&cnt[r], 1);
}

__global__ __launch_bounds__(256) void scan1_k(const int* __restrict__ cnt,
                                               int* __restrict__ start,
                                               int* __restrict__ bsum,
                                               int* __restrict__ blockhist) {
    __shared__ int wtot[4];
    __shared__ int hist[64];
    int t = threadIdx.x, blk = blockIdx.x;
    int i = blk * 256 + t;
    if (t < 64) hist[t] = 0;
    __syncthreads();
    int c = (i < NN) ? cnt[i] : 0;
    if (i < NN) atomicAdd(&hist[c < 63 ? c : 63], 1);
    int lane = t & 63, w = t >> 6;
    int s = c;
    for (int d = 1; d < 64; d <<= 1) {
        int u = __shfl_up(s, d, 64);
        if (lane >= d) s += u;
    }
    if (lane == 63) wtot[w] = s;
    __syncthreads();
    int woff = 0;
    for (int j = 0; j < 4; ++j)
        if (j < w) woff += wtot[j];
    int excl = s - c + woff;
    if (i < NN) start[i] = excl;
    if (t == 255) bsum[blk] = excl + c;
    if (t < 64) blockhist[t * NBLK + blk] = hist[t];
}

__global__ void scan2_k(int* __restrict__ bsum, int* __restrict__ blockhist) {
    __shared__ int wtot[4];
    __shared__ int btot[64];
    int t = threadIdx.x;
    int lane = t & 63, w = t >> 6;
    int v = (t < NBLK) ? bsum[t] : 0;
    int s = v;
    for (int d = 1; d < 64; d <<= 1) {
        int u = __shfl_up(s, d, 64);
        if (lane >= d) s += u;
    }
    if (lane == 63) wtot[w] = s;
    __syncthreads();
    int woff = 0;
    for (int j = 0; j < 4; ++j)
        if (j < w) woff += wtot[j];
    if (t < NBLK) bsum[t] = s - v + woff;
    if (t < 64) {
        int run = 0;
        for (int j = 0; j < NBLK; ++j) {
            int idx = t * NBLK + j;
            int tmp = blockhist[idx];
            blockhist[idx] = run;
            run += tmp;
        }
        btot[t] = run;
    }
    __syncthreads();
    if (t < 64) {
        int bv = btot[t];
        int bs = bv;
        for (int d = 1; d < 64; d <<= 1) {
            int u = __shfl_up(bs, d, 64);
            if (lane >= d) bs += u;
        }
        int base = bs - bv;
        for (int j = 0; j < NBLK; ++j) blockhist[t * NBLK + j] += base;
    }
}

__device__ __forceinline__ void finish_body(int blk, const int* __restrict__ cnt,
                                            int* __restrict__ start,
                                            const int* __restrict__ bsum,
                                            const int* __restrict__ blockhist,
                                            int* __restrict__ perm) {
    __shared__ int hist[64];
    int t = threadIdx.x;
    int i = blk * 256 + t;
    if (t < 64) hist[t] = 0;
    __syncthreads();
    if (i < NN) {
        start[i] += bsum[blk];
        int c = cnt[i];
        int b = c < 63 ? c : 63;
        int rank = atomicAdd(&hist[b], 1);
        perm[blockhist[b * NBLK + blk] + rank] = i;
    }
}

__device__ __forceinline__ void scatter_body(int pb, const int* __restrict__ ei,
                                             const int* __restrict__ flag,
                                             const float* __restrict__ ea,
                                             const int* __restrict__ start,
                                             const int* __restrict__ slot,
                                             uint2* __restrict__ csr) {
    int e = pb * 256 + (int)threadIdx.x;
    if (e >= EE) return;
    int is32 = *flag;
    int r = edge_at(ei, is32, 0, e);
    int c = edge_at(ei, is32, 1, e);
    csr[start[r] + slot[e]] = make_uint2((unsigned)c, __float_as_uint(ea[e]));
}

__device__ __forceinline__ void rowscale_body(int pb, const int* __restrict__ start,
                                              const int* __restrict__ cnt,
                                              const uint2* __restrict__ csr,
                                              float* __restrict__ deginv) {
    int t = threadIdx.x;
    int r = pb * 16 + (t >> 4);
    if (r >= NN) return;
    int fl = t & 15;
    int s = start[r], n = cnt[r];
    float sum = 0.f;
    for (int k = fl; k < n; k += 16) sum += __uint_as_float(csr[s + k].y);
    for (int d = 1; d < 16; d <<= 1) sum += __shfl_xor(sum, d, 16);
    if (fl == 0) deginv[r] = sum > 0.f ? 1.f / sum : 0.f;
}

// Fused prep: cast (3125) | wcvt1 (128) | wcvt2 (32) | detect (1).
__global__ __launch_bounds__(256) void prep_k(const float* __restrict__ W1,
                                              const float* __restrict__ W2,
                                              const float* __restrict__ soft,
                                              const unsigned int* __restrict__ eiw,
                                              int* __restrict__ flag,
                                              short* __restrict__ w1h, short* __restrict__ w1l,
                                              short* __restrict__ w2h, short* __restrict__ w2l,
                                              uint2* __restrict__ sbf) {
    int b = blockIdx.x, t = threadIdx.x;
    if (b < 3125) {  // soft -> bf16
        int i = b * 256 + t;
        float4 f = ((const float4*)soft)[i];
        sbf[i] = make_uint2(packbf2(f.x, f.y), packbf2(f.z, f.w));
    } else if (b < 3125 + 128) {  // W1 split-transpose
        int i = (b - 3125) * 256 + t;
        int k = i / FH, n = i - k * FH;
        float f = W1[i];
        unsigned short h = bf16_rne(f);
        float hf = __uint_as_float((unsigned)h << 16);
        w1h[n * FIN + k] = (short)h;
        w1l[n * FIN + k] = (short)bf16_rne(f - hf);
    } else if (b < 3125 + 128 + 32) {  // W2 split-transpose
        int i = (b - 3125 - 128) * 256 + t;
        int k = i / FC, n = i - k * FC;
        float f = W2[i];
        unsigned short h = bf16_rne(f);
        float hf = __uint_as_float((unsigned)h << 16);
        w2h[n * FH + k] = (short)h;
        w2l[n * FH + k] = (short)bf16_rne(f - hf);
    } else {  // int64-vs-int32 layout detect
        int any = 0;
        for (int i = 1 + 2 * t; i < 2048; i += 512)
            if (eiw[i] != 0u) any = 1;
        if (any) atomicOr(flag, 1);
    }
}

// ---------- GEMM body (R9-exact config) ----------
template <int KDIM, int NCOLT, int NF, int ABF, int CBF>
__device__ __forceinline__ void mgemm2_body(int bx, int cb,
                                            const void* __restrict__ Ap,
                                            const short* __restrict__ Bhi0,
                                            const short* __restrict__ Blo0,
                                            void* __restrict__ Cp, int M) {
    static_assert((size_t)NF * 16 * 72 * 2 * 2 < 49152, "LDS must stay well under 64KB");
    __shared__ short bh[NF * 16][72];
    __shared__ short bl[NF * 16][72];
    const int NSTG = KDIM / 64;
    const int NCH = NF / 2;
    int t = threadIdx.x;
    const short* Bhi = Bhi0 + (size_t)cb * (NF * 16) * KDIM;
    const short* Blo = Blo0 + (size_t)cb * (NF * 16) * KDIM;
    int wid = t >> 6, l = t & 63, l15 = l & 15, lq = l >> 4;
    int row = bx * 64 + wid * 16 + l15;
    bool rv = row < M;
    f32x4 acc[NF];
#pragma unroll
    for (int j = 0; j < NF; ++j) acc[j] = (f32x4){0.f, 0.f, 0.f, 0.f};

    short8v rh[NCH], rl[NCH];
    float4 af[2][4];
    short8v ab_[2][2];
#pragma unroll
    for (int b = 0; b < 2; ++b) {
        if (ABF) {
            ab_[b][0] = (short8v){0, 0, 0, 0, 0, 0, 0, 0};
            ab_[b][1] = (short8v){0, 0, 0, 0, 0, 0, 0, 0};
        } else {
#pragma unroll
            for (int q = 0; q < 4; ++q) af[b][q] = make_float4(0.f, 0.f, 0.f, 0.f);
        }
    }

    auto loadB = [&](int k0) {
#pragma unroll
        for (int j = 0; j < NCH; ++j) {
            int c = t + j * 256;
            int col = c >> 3;
            int kk = (c & 7) * 8;
            rh[j] = *(const short8v*)&Bhi[(size_t)col * KDIM + k0 + kk];
            rl[j] = *(const short8v*)&Blo[(size_t)col * KDIM + k0 + kk];
        }
    };
    auto loadA = [&](int k0, int buf) {
        if (!rv) return;
        if (ABF) {
            const short* A = (const short*)Ap;
            ab_[buf][0] = *(const short8v*)&A[(size_t)row * KDIM + k0 + 8 * lq];
            ab_[buf][1] = *(const short8v*)&A[(size_t)row * KDIM + k0 + 32 + 8 * lq];
        } else {
            const float* A = (const float*)Ap;
            const float4* p0 = (const float4*)&A[(size_t)row * KDIM + k0 + 8 * lq];
            af[buf][0] = p0[0];
            af[buf][1] = p0[1];
            const float4* p1 = (const float4*)&A[(size_t)row * KDIM + k0 + 32 + 8 * lq];
            af[buf][2] = p1[0];
            af[buf][3] = p1[1];
        }
    };

    loadB(0);
    loadA(0, 0);
#pragma unroll
    for (int sg = 0; sg < NSTG; ++sg) {
        __syncthreads();
#pragma unroll
        for (int j = 0; j < NCH; ++j) {
            int c = t + j * 256;
            int col = c >> 3;
            int kk = (c & 7) * 8;
            *(short8v*)&bh[col][kk] = rh[j];
            *(short8v*)&bl[col][kk] = rl[j];
        }
        __syncthreads();
        if (sg + 1 < NSTG) {
            loadB((sg + 1) * 64);
            loadA((sg + 1) * 64, (sg + 1) & 1);
        }
        int cbuf = sg & 1;
#pragma unroll
        for (int ks = 0; ks < 2; ++ks) {
            short8v ahi, alo;
            if (ABF) {
                ahi = ab_[cbuf][ks];
            } else {
                float av[8];
                float4 xa = af[cbuf][ks * 2], xb = af[cbuf][ks * 2 + 1];
                av[0] = xa.x; av[1] = xa.y; av[2] = xa.z; av[3] = xa.w;
                av[4] = xb.x; av[5] = xb.y; av[6] = xb.z; av[7] = xb.w;
#pragma unroll
                for (int e = 0; e < 8; ++e) {
                    unsigned short h = bf16_rne(av[e]);
                    float hf = __uint_as_float((unsigned)h << 16);
                    ahi[e] = (short)h;
                    alo[e] = (short)bf16_rne(av[e] - hf);
                }
            }
#pragma unroll
            for (int j = 0; j < NF; ++j) {
                int col = j * 16 + l15;
                short8v fh = *(const short8v*)&bh[col][ks * 32 + 8 * lq];
                short8v fo = *(const short8v*)&bl[col][ks * 32 + 8 * lq];
                acc[j] = __builtin_amdgcn_mfma_f32_16x16x32_bf16(ahi, fh, acc[j], 0, 0, 0);
                acc[j] = __builtin_amdgcn_mfma_f32_16x16x32_bf16(ahi, fo, acc[j], 0, 0, 0);
                if (!ABF)
                    acc[j] = __builtin_amdgcn_mfma_f32_16x16x32_bf16(alo, fh, acc[j], 0, 0, 0);
            }
        }
    }
    int rbase = bx * 64 + wid * 16 + 4 * lq;
#pragma unroll
    for (int j = 0; j < NF; ++j) {
        int col = cb * (NF * 16) + j * 16 + l15;
#pragma unroll
        for (int e = 0; e < 4; ++e) {
            int r = rbase + e;
            if (r < M) {
                if (CBF)
                    ((unsigned short*)Cp)[(size_t)r * NCOLT + col] = bf16_rne(acc[j][e]);
                else
                    ((float*)Cp)[(size_t)r * NCOLT + col] = acc[j][e];
            }
        }
    }
}

__device__ __forceinline__ void gemm1_v(int v, const float* __restrict__ x,
                                        const short* __restrict__ w1h,
                                        const short* __restrict__ w1l,
                                        unsigned short* __restrict__ t1) {
    mgemm2_body<FIN, FH, 4, 0, 1>(v % G1X, v / G1X, x, w1h, w1l, t1, NN);
}

// ---------- spmm bodies ----------
__device__ __forceinline__ void spmm128b_body(int pb, const int* __restrict__ perm,
                                              const int* __restrict__ start,
                                              const int* __restrict__ cnt,
                                              const float* __restrict__ deginv,
                                              const uint2* __restrict__ csr,
                                              const uint2* __restrict__ mb,
                                              uint2* __restrict__ outb,
                                              const float* __restrict__ bias) {
    int t = threadIdx.x;
    int p = pb * 8 + (t >> 5);
    if (p >= NN) return;
    int r = perm[p];
    int fl = t & 31;
    float4 acc = make_float4(0.f, 0.f, 0.f, 0.f);
    int s = start[r], n = cnt[r];
    int k = 0;
    for (; k + 8 <= n; k += 8) {
        uint2 ev[8];
        uint2 gv[8];
#pragma unroll
        for (int u = 0; u < 8; ++u) ev[u] = csr[s + k + u];
#pragma unroll
        for (int u = 0; u < 8; ++u) gv[u] = mb[(size_t)ev[u].x * 32 + fl];
#pragma unroll
        for (int u = 0; u < 8; ++u) {
            float v = __uint_as_float(ev[u].y);
            acc.x = fmaf(v, __uint_as_float(gv[u].x << 16), acc.x);
            acc.y = fmaf(v, __uint_as_float(gv[u].x & 0xFFFF0000u), acc.y);
            acc.z = fmaf(v, __uint_as_float(gv[u].y << 16), acc.z);
            acc.w = fmaf(v, __uint_as_float(gv[u].y & 0xFFFF0000u), acc.w);
        }
    }
    for (; k < n; ++k) {
        uint2 e = csr[s + k];
        float v = __uint_as_float(e.y);
        uint2 g = mb[(size_t)e.x * 32 + fl];
        acc.x = fmaf(v, __uint_as_float(g.x << 16), acc.x);
        acc.y = fmaf(v, __uint_as_float(g.x & 0xFFFF0000u), acc.y);
        acc.z = fmaf(v, __uint_as_float(g.y << 16), acc.z);
        acc.w = fmaf(v, __uint_as_float(g.y & 0xFFFF0000u), acc.w);
    }
    float dv = deginv[r];
    float4 b = ((const float4*)bias)[fl];
    acc.x = fmaxf(fmaf(acc.x, dv, b.x), 0.f);
    acc.y = fmaxf(fmaf(acc.y, dv, b.y), 0.f);
    acc.z = fmaxf(fmaf(acc.z, dv, b.z), 0.f);
    acc.w = fmaxf(fmaf(acc.w, dv, b.w), 0.f);
    outb[(size_t)r * 32 + fl] = make_uint2(packbf2(acc.x, acc.y), packbf2(acc.z, acc.w));
}

// SpMM F=64 bf16-in: quarter-wave; optional bias; bf16 or f32 out.
__device__ __forceinline__ void spmm64b_body(int pb, const int* __restrict__ perm,
                                             const int* __restrict__ start,
                                             const int* __restrict__ cnt,
                                             const float* __restrict__ deginv,
                                             const uint2* __restrict__ csr,
                                             const uint2* __restrict__ mb,
                                             void* __restrict__ outp,
                                             const float* __restrict__ bias,
                                             int f32out) {
    int t = threadIdx.x;
    int p = pb * 16 + (t >> 4);
    if (p >= NN) return;
    int r = perm[p];
    int fl = t & 15;
    float4 acc = make_float4(0.f, 0.f, 0.f, 0.f);
    int s = start[r], n = cnt[r];
    int k = 0;
    for (; k + 8 <= n; k += 8) {
        uint2 ev[8];
        uint2 gv[8];
#pragma unroll
        for (int u = 0; u < 8; ++u) ev[u] = csr[s + k + u];
#pragma unroll
        for (int u = 0; u < 8; ++u) gv[u] = mb[(size_t)ev[u].x * 16 + fl];
#pragma unroll
        for (int u = 0; u < 8; ++u) {
            float v = __uint_as_float(ev[u].y);
            acc.x = fmaf(v, __uint_as_float(gv[u].x << 16), acc.x);
            acc.y = fmaf(v, __uint_as_float(gv[u].x & 0xFFFF0000u), acc.y);
            acc.z = fmaf(v, __uint_as_float(gv[u].y << 16), acc.z);
            acc.w = fmaf(v, __uint_as_float(gv[u].y & 0xFFFF0000u), acc.w);
        }
    }
    for (; k < n; ++k) {
        uint2 e = csr[s + k];
        float v = __uint_as_float(e.y);
        uint2 g = mb[(size_t)e.x * 16 + fl];
        acc.x = fmaf(v, __uint_as_float(g.x << 16), acc.x);
        acc.y = fmaf(v, __uint_as_float(g.x & 0xFFFF0000u), acc.y);
        acc.z = fmaf(v, __uint_as_float(g.y << 16), acc.z);
        acc.w = fmaf(v, __uint_as_float(g.y & 0xFFFF0000u), acc.w);
    }
    float dv = deginv[r];
    acc.x *= dv; acc.y *= dv; acc.z *= dv; acc.w *= dv;
    if (bias) {
        float4 b = ((const float4*)bias)[fl];
        acc.x += b.x; acc.y += b.y; acc.z += b.z; acc.w += b.w;
    }
    if (f32out) {
        ((float4*)outp)[(size_t)r * 16 + fl] = acc;
    } else {
        ((uint2*)outp)[(size_t)r * 16 + fl] =
            make_uint2(packbf2(acc.x, acc.y), packbf2(acc.z, acc.w));
    }
}

// ---------- fused kernels ----------

// P1: GEMM1 slice [0,782) || accum (3125) — GEMM-anchored half FIRST (R18
// proved accum-first regresses 49->56us: atomic blocks flood the CUs).
__global__ __launch_bounds__(256) void p1_k(const float* __restrict__ x,
                                            const short* __restrict__ w1h,
                                            const short* __restrict__ w1l,
                                            unsigned short* __restrict__ t1,
                                            const int* __restrict__ ei,
                                            const int* __restrict__ flag,
                                            int* __restrict__ cnt,
                                            int* __restrict__ slot) {
    int b = blockIdx.x;
    if (b < G1_S1) gemm1_v(b, x, w1h, w1l, t1);
    else accum_body(b - G1_S1, ei, flag, cnt, slot);
}

// P2: GEMM1 slice [782,882) || finish (196)
__global__ __launch_bounds__(256) void p2_k(const float* __restrict__ x,
                                            const short* __restrict__ w1h,
                                            const short* __restrict__ w1l,
                                            unsigned short* __restrict__ t1,
                                            const int* __restrict__ cnt,
                                            int* __restrict__ start,
                                            const int* __restrict__ bsum,
                                            const int* __restrict__ bhist,
                                            int* __restrict__ perm) {
    int b = blockIdx.x;
    if (b < G1_S2 - G1_S1) gemm1_v(G1_S1 + b, x, w1h, w1l, t1);
    else finish_body(b - (G1_S2 - G1_S1), cnt, start, bsum, bhist, perm);
}

// P3: GEMM1 slice [882,1382) || scatter (3125)
__global__ __launch_bounds__(256) void p3_k(const float* __restrict__ x,
                                            const short* __restrict__ w1h,
                                            const short* __restrict__ w1l,
                                            unsigned short* __restrict__ t1,
                                            const int* __restrict__ ei,
                                            const int* __restrict__ flag,
                                            const float* __restrict__ ea,
                                            const int* __restrict__ start,
                                            const int* __restrict__ slot,
                                            uint2* __restrict__ csr) {
    int b = blockIdx.x;
    if (b < G1_S3 - G1_S2) gemm1_v(G1_S2 + b, x, w1h, w1l, t1);
    else scatter_body(b - (G1_S3 - G1_S2), ei, flag, ea, start, slot, csr);
}

// P4: GEMM1 slice [1382,1564) || rowscale (3125)
__global__ __launch_bounds__(256) void p4_k(const float* __restrict__ x,
                                            const short* __restrict__ w1h,
                                            const short* __restrict__ w1l,
                                            unsigned short* __restrict__ t1,
                                            const int* __restrict__ start,
                                            const int* __restrict__ cnt,
                                            const uint2* __restrict__ csr,
                                            float* __restrict__ dinv) {
    int b = blockIdx.x;
    if (b < G1_TOT - G1_S3) gemm1_v(G1_S3 + b, x, w1h, w1l, t1);
    else rowscale_body(b - (G1_TOT - G1_S3), start, cnt, csr, dinv);
}

// F2: spmm128b (6250) || LPA it0 (sbf -> lA)
__global__ __launch_bounds__(256) void f2_k(const int* __restrict__ perm,
                                            const int* __restrict__ start,
                                            const int* __restrict__ cnt,
                                            const float* __restrict__ dinv,
                                            const uint2* __restrict__ csr,
                                            const uint2* __restrict__ t1,
                                            uint2* __restrict__ h,
                                            const float* __restrict__ b1,
                                            const uint2* __restrict__ sbf,
                                            uint2* __restrict__ lA) {
    int b = blockIdx.x;
    if (b < SP128B)
        spmm128b_body(b, perm, start, cnt, dinv, csr, t1, h, b1);
    else
        spmm64b_body(b - SP128B, perm, start, cnt, dinv, csr, sbf, lA, nullptr, 0);
}

// F3: GEMM2 -> t2 bf16 (782) || LPA it1 (lA -> lB)
__global__ __launch_bounds__(256) void f3_k(const unsigned short* __restrict__ h,
                                            const short* __restrict__ w2h,
                                            const short* __restrict__ w2l,
                                            unsigned short* __restrict__ t2,
                                            const int* __restrict__ perm,
                                            const int* __restrict__ start,
                                            const int* __restrict__ cnt,
                                            const float* __restrict__ dinv,
                                            const uint2* __restrict__ csr,
                                            const uint2* __restrict__ lA,
                                            uint2* __restrict__ lB) {
    int b = blockIdx.x;
    if (b < G1X)
        mgemm2_body<FH, FC, 4, 1, 1>(b, 0, h, w2h, w2l, t2, NN);
    else
        spmm64b_body(b - G1X, perm, start, cnt, dinv, csr, lA, lB, nullptr, 0);
}

// F4: conv2 spmm from bf16 t2 (+b2, f32 out) (3125) || LPA it2 (lB -> lA)
__global__ __launch_bounds__(256) void f4_k(const int* __restrict__ perm,
                                            const int* __restrict__ start,
                                            const int* __restrict__ cnt,
                                            const float* __restrict__ dinv,
                                            const uint2* __restrict__ csr,
                                            const uint2* __restrict__ t2b,
                                            float* __restrict__ out,
                                            const float* __restrict__ b2,
                                            const uint2* __restrict__ lB,
                                            uint2* __restrict__ lA) {
    int b = blockIdx.x;
    if (b < SPB)
        spmm64b_body(b, perm, start, cnt, dinv, csr, t2b, out, b2, 1);
    else
        spmm64b_body(b - SPB, perm, start, cnt, dinv, csr, lB, lA, nullptr, 0);
}

// Standalone LPA kernel for iters 3..9.
__global__ __launch_bounds__(256) void spmm64b_k(const int* __restrict__ perm,
                                                 const int* __restrict__ start,
                                                 const int* __restrict__ cnt,
                                                 const float* __restrict__ deginv,
                                                 const uint2* __restrict__ csr,
                                                 const uint2* __restrict__ mb,
                                                 void* __restrict__ outp,
                                                 int f32out) {
    spmm64b_body(blockIdx.x, perm, start, cnt, deginv, csr, mb, outp, nullptr, f32out);
}

extern "C" void kernel_launch(void* const* d_in, const int* in_sizes, int n_in,
                              void* d_out, int out_size, void* d_ws, size_t ws_size,
                              hipStream_t stream) {
    const float* x    = (const float*)d_in[0];
    const float* soft = (const float*)d_in[1];
    const int*   ei   = (const int*)d_in[2];
    const float* ea   = (const float*)d_in[3];
    const float* W1   = (const float*)d_in[4];
    const float* b1   = (const float*)d_in[5];
    const float* W2   = (const float*)d_in[6];
    const float* b2   = (const float*)d_in[7];
    float* out  = (float*)d_out;                 // [N, C]
    float* labB = out + (size_t)NN * FC;         // [N, C] second output

    char* ws = (char*)d_ws;
    size_t off = 0;
    auto alloc = [&](size_t b) { size_t o = off; off += (b + 255) & ~(size_t)255; return o; };
    size_t o_misc  = alloc(256);                      // [0] = layout flag
    size_t o_cnt   = alloc((size_t)NN * 4);
    size_t zero_end = off;
    size_t o_start = alloc((size_t)NN * 4);
    size_t o_perm  = alloc((size_t)NN * 4);
    size_t o_dinv  = alloc((size_t)NN * 4);
    size_t o_bsum  = alloc((size_t)NBLK * 4);
    size_t o_bhist = alloc((size_t)64 * NBLK * 4);
    size_t o_slot  = alloc((size_t)EE * 4);
    size_t o_csr   = alloc((size_t)EE * 8);           // packed uint2 {col, raw ea}
    size_t o_w1h   = alloc((size_t)FIN * FH * 2);     // W1^T split-bf16
    size_t o_w1l   = alloc((size_t)FIN * FH * 2);
    size_t o_w2h   = alloc((size_t)FH * FC * 2);      // W2^T split-bf16
    size_t o_w2l   = alloc((size_t)FH * FC * 2);
    size_t o_t1    = alloc((size_t)NN * FH * 2);      // xW1, bf16
    size_t o_h     = alloc((size_t)NN * FH * 2);      // relu(spmm)+b1, bf16
    size_t o_t2    = alloc((size_t)NN * FC * 2);      // hW2, bf16
    size_t o_sbf   = alloc((size_t)NN * FC * 2);      // soft_labels bf16
    size_t o_lA    = alloc((size_t)NN * FC * 2);      // LPA ping
    size_t o_lB    = alloc((size_t)NN * FC * 2);      // LPA pong
    if (off > ws_size) return;  // insufficient scratch -> visible failure

    int*   misc  = (int*)(ws + o_misc);
    int*   cnt   = (int*)(ws + o_cnt);
    int*   start = (int*)(ws + o_start);
    int*   perm  = (int*)(ws + o_perm);
    float* dinv  = (float*)(ws + o_dinv);
    int*   bsum  = (int*)(ws + o_bsum);
    int*   bhist = (int*)(ws + o_bhist);
    int*   slot  = (int*)(ws + o_slot);
    uint2* csr   = (uint2*)(ws + o_csr);
    short* w1h   = (short*)(ws + o_w1h);
    short* w1l   = (short*)(ws + o_w1l);
    short* w2h   = (short*)(ws + o_w2h);
    short* w2l   = (short*)(ws + o_w2l);
    unsigned short* t1 = (unsigned short*)(ws + o_t1);
    uint2* h     = (uint2*)(ws + o_h);
    unsigned short* t2 = (unsigned short*)(ws + o_t2);
    uint2* sbf   = (uint2*)(ws + o_sbf);
    uint2* lA    = (uint2*)(ws + o_lA);
    uint2* lB    = (uint2*)(ws + o_lB);

    hipMemsetAsync(d_ws, 0, zero_end, stream);
    prep_k<<<3125 + 128 + 32 + 1, 256, 0, stream>>>(W1, W2, soft, (const unsigned int*)ei,
                                                    &misc[0], w1h, w1l, w2h, w2l, sbf);

    // CSR chain, each stage carrying a GEMM1 slice sized ~to its duration.
    p1_k<<<G1_S1 + EBLK, 256, 0, stream>>>(x, w1h, w1l, t1, ei, misc, cnt, slot);
    scan1_k<<<NBLK, 256, 0, stream>>>(cnt, start, bsum, bhist);
    scan2_k<<<1, 256, 0, stream>>>(bsum, bhist);
    p2_k<<<(G1_S2 - G1_S1) + NBLK, 256, 0, stream>>>(x, w1h, w1l, t1, cnt, start, bsum,
                                                     bhist, perm);
    p3_k<<<(G1_S3 - G1_S2) + EBLK, 256, 0, stream>>>(x, w1h, w1l, t1, ei, misc, ea,
                                                     start, slot, csr);
    p4_k<<<(G1_TOT - G1_S3) + SPB, 256, 0, stream>>>(x, w1h, w1l, t1, start, cnt, csr,
                                                     dinv);

    // Fused GCN stage || independent LPA iteration.
    f2_k<<<SP128B + SPB, 256, 0, stream>>>(perm, start, cnt, dinv, csr,
                                           (const uint2*)t1, h, b1, sbf, lA);
    f3_k<<<G1X + SPB, 256, 0, stream>>>((const unsigned short*)h, w2h, w2l, t2,
                                        perm, start, cnt, dinv, csr, lA, lB);
    f4_k<<<SPB + SPB, 256, 0, stream>>>(perm, start, cnt, dinv, csr,
                                        (const uint2*)t2, out, b2, lB, lA);

    // LPA iters 3..9 standalone (it9 writes f32 to labB).
    const uint2* src = lA;
    uint2* dst = lB;
    for (int it = 3; it < LPA_ITERS; ++it) {
        int last = (it == LPA_ITERS - 1);
        spmm64b_k<<<SPB, 256, 0, stream>>>(perm, start, cnt, dinv, csr, src,
                                           last ? (void*)labB : (void*)dst, last);
        src = dst;
        dst = (dst == lA) ? lB : lA;
    }
}